// Round 15
// baseline (2075.735 us; speedup 1.0000x reference)
//
#include <hip/hip_runtime.h>
#include <stdint.h>

// LSTMTimeDecoder on MI355X — round 15.
// Chunked dataflow. r14's floor was bulk-rendezvous consume (validate 16KB
// before any gates work + early-load staleness retries). Now:
//  * member-major exchange layout [member][16x32]: member m writes ONLY its
//    region -> zero cross-wg write hazards; repoison is own-region, own-wave
//    WAW ordered by the existing vmcnt chain.
//  * consumers load gates A-fragments DIRECTLY to registers: 8 chunks/wave
//    (K-split: wave owns 2 gates x 8 chunks, partials summed via gbufP),
//    staggered vmcnt(7-j) + per-chunk sentinel check + masked 16B retry +
//    MFMAs. A late member stalls only its chunk. No hlds / scatter / B2,B3.
//  * loads issued ~300-450cy after F (delay = out-proj partials / sum-store /
//    sleep(4)) so L3 services them after peers' stores land.
//  * out-proj: waves 2,3 K-half partials -> obufP (double-buffered); wave 0
//    sums+stores row t-2 next iter. No hs buffer, no k_out.
// Sentinel 3-slot sc0sc1 protocol otherwise as r6-r14 (verified).

#define HD 512
#define BD 256
#define SD 512
#define OD 128
#define SENT 0xFF80FF80u

typedef __attribute__((ext_vector_type(8))) short short8;
typedef __attribute__((ext_vector_type(4))) float f32x4;
typedef __attribute__((ext_vector_type(4))) unsigned int u32x4;

static __device__ __forceinline__ unsigned short f2bf(float x) {
  unsigned int u = __float_as_uint(x);
  u += 0x7fffu + ((u >> 16) & 1u);
  return (unsigned short)(u >> 16);
}
static __device__ __forceinline__ float sigm(float x) {
  return 1.0f / (1.0f + __expf(-x));
}
static __device__ __forceinline__ float tanhf_(float x) {
  x = fminf(15.f, fmaxf(-15.f, x));
  float e = __expf(2.f * x);
  return (e - 1.f) / (e + 1.f);
}
static __device__ __forceinline__ int badchk8(short8 v) {
  u32x4 w;
  __builtin_memcpy(&w, &v, 16);
  return (w.x == SENT) | (w.y == SENT) | (w.z == SENT) | (w.w == SENT);
}
#define KEEPALIVE(x) asm volatile("" : "+v"(x))

// ---------------- prep kernels (verified rounds 1-14) ----------------
__global__ __launch_bounds__(256) void k_cvt(const float* __restrict__ whh,
                                             const float* __restrict__ linw,
                                             unsigned short* __restrict__ whhb,
                                             unsigned short* __restrict__ linwb) {
  int i = blockIdx.x * 256 + threadIdx.x;
  whhb[i] = f2bf(whh[i]);
  if (i < OD * HD) linwb[i] = f2bf(linw[i]);
}

__global__ __launch_bounds__(256) void k_td(const float* __restrict__ t,
                                            float* __restrict__ td) {
  int i = blockIdx.x * 256 + threadIdx.x;
  float v = 0.f;
  if (i >= BD) v = t[i] - t[i - BD];
  td[i] = v;
}

__global__ __launch_bounds__(256) void k_u(const float* __restrict__ wih,
                                           const float* __restrict__ tw,
                                           const float* __restrict__ tb,
                                           const float* __restrict__ bih,
                                           const float* __restrict__ bhh,
                                           float* __restrict__ u,
                                           float* __restrict__ ub) {
  int gc = blockIdx.x * 256 + threadIdx.x;
  const float4* w4 = (const float4*)(wih + (size_t)gc * (2 * HD) + HD);
  const float4* t4 = (const float4*)tw;
  const float4* b4 = (const float4*)tb;
  float a = 0.f, b = 0.f;
  for (int k = 0; k < HD / 4; ++k) {
    float4 w = w4[k], tv = t4[k], bv = b4[k];
    a += w.x * tv.x + w.y * tv.y + w.z * tv.z + w.w * tv.w;
    b += w.x * bv.x + w.y * bv.y + w.z * bv.z + w.w * bv.w;
  }
  u[gc] = a;
  ub[gc] = b + bih[gc] + bhh[gc];
}

__global__ __launch_bounds__(1024) void k_cw(const float* __restrict__ C,
                                             const float* __restrict__ wih,
                                             const float* __restrict__ ub,
                                             float* __restrict__ CW) {
  int gc = blockIdx.x * 64 + (threadIdx.x & 63);
  int b  = blockIdx.y * 16 + (threadIdx.x >> 6);
  const float4* c4 = (const float4*)(C + (size_t)b * HD);
  const float4* w4 = (const float4*)(wih + (size_t)gc * (2 * HD));
  float acc = 0.f;
  for (int k = 0; k < HD / 4; ++k) {
    float4 cv = c4[k], wv = w4[k];
    acc += cv.x * wv.x + cv.y * wv.y + cv.z * wv.z + cv.w * wv.w;
  }
  CW[(size_t)b * (4 * HD) + gc] = acc + ub[gc];
}

__global__ __launch_bounds__(256) void k_poison(unsigned int* __restrict__ hbuf) {
  u32x4 s = {SENT, SENT, SENT, SENT};
  unsigned int* p = hbuf + (size_t)(blockIdx.x * 256 + threadIdx.x) * 4;
  asm volatile("global_store_dwordx4 %0, %1, off sc0 sc1" :: "v"(p), "v"(s) : "memory");
}

// ---------------- main recurrent kernel ----------------
__global__ __launch_bounds__(256, 1) void k_main(
    const float* __restrict__ CW, const float* __restrict__ u,
    const float* __restrict__ td, const unsigned short* __restrict__ whhb,
    const unsigned short* __restrict__ linwb, const float* __restrict__ linb,
    unsigned short* __restrict__ hbuf, float* __restrict__ out)
{
  __shared__ float gbufP[4][2][16][33];                    // 16.9KB gate partials
  __shared__ float obufP[2][2][16][16];                    // 4KB out partials
  __shared__ __align__(16) unsigned short lwlds[16 * HD];  // 16KB linW slice

  const int tid  = threadIdx.x;
  const int lane = tid & 63;
  const int wv   = tid >> 6;
  const int gid  = blockIdx.x & 15;   // batch group
  const int m    = blockIdx.x >> 4;   // member: h-cols [m*32, m*32+32)

  const int ga    = (wv >> 1) * 2;    // this wave's gates: ga, ga+1
  const int khalf = wv & 1;           // k-chunks (members) khalf*8 .. +8

  // ---- W_hh fragments -> registers via asm: 2 gates x 2 col-halves x 8 ----
  short8 wA0[8], wA1[8], wB0[8], wB1[8];
  {
    #pragma unroll
    for (int j = 0; j < 8; ++j) {
      size_t ko = (size_t)((khalf * 8 + j) * 32 + (lane >> 4) * 8);
      const unsigned short* pA0 =
          whhb + (size_t)(ga * HD + m * 32 + (lane & 15)) * HD + ko;
      const unsigned short* pB0 = pA0 + (size_t)HD * HD;
      asm volatile(
          "global_load_dwordx4 %0, %4, off\n\t"
          "global_load_dwordx4 %1, %5, off\n\t"
          "global_load_dwordx4 %2, %6, off\n\t"
          "global_load_dwordx4 %3, %7, off"
          : "=&v"(wA0[j]), "=&v"(wA1[j]), "=&v"(wB0[j]), "=&v"(wB1[j])
          : "v"(pA0), "v"(pA0 + 16 * HD), "v"(pB0), "v"(pB0 + 16 * HD)
          : "memory");
    }
  }

  // ---- linW slice -> LDS (r14-verified staging, XOR image) ----
  if (m < 8) {
    for (int i = tid; i < 16 * 64; i += 256) {
      int rl = i >> 6, c = i & 63;
      *(short8*)((char*)lwlds + (size_t)rl * 1024 + (size_t)c * 16) =
          *(const short8*)((const char*)linwb + (size_t)(m * 16 + rl) * 1024 +
                           (size_t)((c ^ (rl & 7)) * 16));
    }
  }

  // ---- per-thread cell constants ----
  const int r    = tid >> 4;
  const int jl0  = (tid & 15) * 2;
  const int grow = gid * 16 + r;
  const int col0 = m * 32 + jl0;
  float cwr[8], ur[8];
  #pragma unroll
  for (int g = 0; g < 4; ++g) {
    int col = g * HD + col0;
    cwr[g * 2]     = CW[(size_t)grow * (4 * HD) + col];
    cwr[g * 2 + 1] = CW[(size_t)grow * (4 * HD) + col + 1];
    ur[g * 2]      = u[col];
    ur[g * 2 + 1]  = u[col + 1];
  }
  float cs0 = 0.f, cs1 = 0.f;
  float lb = 0.f;
  if (m < 8) lb = linb[m * 16 + (lane & 15)];

  char* hb = (char*)hbuf + (size_t)gid * 49152;   // 3 slots x 16KB (member-major)

  const int arow  = lane & 15;
  const int akoff = lane >> 4;
  const int aoff  = arow * 64 + akoff * 16;       // within a member's 1KB region
  const int lrow  = lane & 15;
  const int lxor  = (lrow & 7) << 4;
  const int rr    = (lane >> 4) * 4;
  const int cc    = lane & 15;

  short8 a0{}, a1{}, a2{}, a3{}, a4{}, a5{}, a6{}, a7{};
  float  tdn = 0.f;

  #pragma unroll
  for (int i = 0; i < 8; ++i) { KEEPALIVE(cwr[i]); KEEPALIVE(ur[i]); }
  KEEPALIVE(lb);
  asm volatile("s_waitcnt vmcnt(0)" ::: "memory");
  __builtin_amdgcn_sched_barrier(0);
  __syncthreads();   // lwlds staged

#define RETRY_CHUNK(J)                                                        \
  {                                                                           \
    int bad = badchk8(a##J);                                                  \
    int guard = 0;                                                            \
    while (__any(bad)) {                                                      \
      if (++guard > (1 << 16)) break;                                         \
      __builtin_amdgcn_s_sleep(2);                                            \
      if (bad)                                                                \
        asm volatile("global_load_dwordx4 %0, %1, off sc0 sc1"               \
                     : "=&v"(a##J) : "v"(csrc + (J) * 1024) : "memory");      \
      asm volatile("s_waitcnt vmcnt(0)" ::: "memory");                        \
      __builtin_amdgcn_sched_barrier(0);                                      \
      bad = badchk8(a##J);                                                    \
    }                                                                         \
  }

#define GATE_CHUNK(J, REMSTR)                                                 \
  {                                                                           \
    asm volatile("s_waitcnt vmcnt(" REMSTR ")" ::: "memory");                 \
    __builtin_amdgcn_sched_barrier(0);                                        \
    RETRY_CHUNK(J)                                                            \
    accA0 = __builtin_amdgcn_mfma_f32_16x16x32_bf16(a##J, wA0[J], accA0, 0, 0, 0); \
    accA1 = __builtin_amdgcn_mfma_f32_16x16x32_bf16(a##J, wA1[J], accA1, 0, 0, 0); \
    accB0 = __builtin_amdgcn_mfma_f32_16x16x32_bf16(a##J, wB0[J], accB0, 0, 0, 0); \
    accB1 = __builtin_amdgcn_mfma_f32_16x16x32_bf16(a##J, wB1[J], accB1, 0, 0, 0); \
  }

#define OP_CHUNK(J)                                                           \
  {                                                                           \
    short8 bf = *(const short8*)((const char*)lwlds + (size_t)lrow * 1024 +   \
        (size_t)((((khalf * 8 + (J)) * 64 + akoff * 16)) ^ lxor));            \
    os = __builtin_amdgcn_mfma_f32_16x16x32_bf16(a##J, bf, os, 0, 0, 0);      \
  }

#define ISSUE_CHUNK(J)                                                        \
  asm volatile("global_load_dwordx4 %0, %1, off sc0 sc1"                      \
               : "=&v"(a##J) : "v"(nsrc + (J) * 1024) : "memory");

  for (int t = 0; t < SD; ++t) {
    const size_t oC = (size_t)(t % 3) * 16384;
    const size_t oN = (size_t)((t + 1) % 3) * 16384;
    const size_t oR = (size_t)((t + 2) % 3) * 16384;   // h_{t-1}'s slot

    // ---- gates: staggered per-chunk consume + MFMA ----
    f32x4 accA0 = {0.f, 0.f, 0.f, 0.f}, accA1 = {0.f, 0.f, 0.f, 0.f};
    f32x4 accB0 = {0.f, 0.f, 0.f, 0.f}, accB1 = {0.f, 0.f, 0.f, 0.f};
    if (t > 0) {
      const char* csrc = hb + oC + (size_t)(khalf * 8) * 1024 + aoff;
      GATE_CHUNK(0, "7")
      GATE_CHUNK(1, "6")
      GATE_CHUNK(2, "5")
      GATE_CHUNK(3, "4")
      GATE_CHUNK(4, "3")
      GATE_CHUNK(5, "2")
      GATE_CHUNK(6, "1")
      GATE_CHUNK(7, "0")
    }

    // ---- gate partials -> gbufP ----
    #pragma unroll
    for (int qq = 0; qq < 4; ++qq) {
      gbufP[wv][0][rr + qq][cc]      = accA0[qq];
      gbufP[wv][0][rr + qq][16 + cc] = accA1[qq];
      gbufP[wv][1][rr + qq][cc]      = accB0[qq];
      gbufP[wv][1][rr + qq][16 + cc] = accB1[qq];
    }
    asm volatile("s_waitcnt lgkmcnt(0)" ::: "memory");
    __builtin_amdgcn_s_barrier();          // B1: all waves validated all members

    // ---- repoison own region of h_{t-1}'s slot (justified post-B1) ----
    {
      char* pp = hb + oR + (size_t)m * 1024 + (size_t)tid * 4;
      unsigned int s = SENT;
      asm volatile("global_store_dword %0, %1, off sc0 sc1" :: "v"(pp), "v"(s) : "memory");
    }

    // ---- cell (2 elems/thread); gate g = partials of its two waves ----
    unsigned int hp;
    {
      float tdv = (t > 0) ? tdn : 0.f;     // tdn retired by GATE_CHUNK(7)'s vmcnt(0)
      float p0i = gbufP[0][0][r][jl0]     + gbufP[1][0][r][jl0]     + cwr[0] + tdv * ur[0];
      float p1i = gbufP[0][0][r][jl0 + 1] + gbufP[1][0][r][jl0 + 1] + cwr[1] + tdv * ur[1];
      float p0f = gbufP[0][1][r][jl0]     + gbufP[1][1][r][jl0]     + cwr[2] + tdv * ur[2];
      float p1f = gbufP[0][1][r][jl0 + 1] + gbufP[1][1][r][jl0 + 1] + cwr[3] + tdv * ur[3];
      float p0g = gbufP[2][0][r][jl0]     + gbufP[3][0][r][jl0]     + cwr[4] + tdv * ur[4];
      float p1g = gbufP[2][0][r][jl0 + 1] + gbufP[3][0][r][jl0 + 1] + cwr[5] + tdv * ur[5];
      float p0o = gbufP[2][1][r][jl0]     + gbufP[3][1][r][jl0]     + cwr[6] + tdv * ur[6];
      float p1o = gbufP[2][1][r][jl0 + 1] + gbufP[3][1][r][jl0 + 1] + cwr[7] + tdv * ur[7];
      cs0 = sigm(p0f) * cs0 + sigm(p0i) * tanhf_(p0g);
      cs1 = sigm(p1f) * cs1 + sigm(p1i) * tanhf_(p1g);
      float h0 = sigm(p0o) * tanhf_(cs0);
      float h1 = sigm(p1o) * tanhf_(cs1);
      hp = (unsigned int)f2bf(h0) | ((unsigned int)f2bf(h1) << 16);
    }

    // ---- F: h_{t+1} store into own region (member-major) ----
    {
      char* hsl = hb + oN + (size_t)m * 1024 + (size_t)(r * 64 + jl0 * 2);
      asm volatile("global_store_dword %0, %1, off sc0 sc1" :: "v"(hsl), "v"(hp) : "memory");
    }

    // ---- delay window (covers peers' store landing), then issue loads ----
    const char* nsrc = hb + oN + (size_t)(khalf * 8) * 1024 + aoff;
    if (m < 8 && wv >= 2 && t > 0) {
      // out-proj K-half partial for row t-1 (uses a0..a7 = h_t, then releases)
      f32x4 os = {0.f, 0.f, 0.f, 0.f};
      OP_CHUNK(0) OP_CHUNK(1) OP_CHUNK(2) OP_CHUNK(3)
      OP_CHUNK(4) OP_CHUNK(5) OP_CHUNK(6) OP_CHUNK(7)
      #pragma unroll
      for (int qq = 0; qq < 4; ++qq)
        obufP[t & 1][khalf][rr + qq][cc] = os[qq];
      // td + consume loads for h_{t+1}
      int tt = (t + 1 < SD) ? (t + 1) : t;
      const float* ta = td + (size_t)tt * BD + grow;
      asm volatile("global_load_dword %0, %1, off" : "=&v"(tdn) : "v"(ta) : "memory");
      ISSUE_CHUNK(0) ISSUE_CHUNK(1) ISSUE_CHUNK(2) ISSUE_CHUNK(3)
      ISSUE_CHUNK(4) ISSUE_CHUNK(5) ISSUE_CHUNK(6) ISSUE_CHUNK(7)
    } else {
      __builtin_amdgcn_s_sleep(4);   // ~256 cy
      if (m < 8 && wv == 0 && t >= 2) {
        // sum+store out row t-2 (partials written iter t-1; synced by B1)
        float* ob = out + (size_t)(t - 2) * (BD * OD) + (size_t)(gid * 16) * OD + m * 16;
        #pragma unroll
        for (int qq = 0; qq < 4; ++qq) {
          float v = obufP[(t - 1) & 1][0][rr + qq][cc] +
                    obufP[(t - 1) & 1][1][rr + qq][cc] + lb;
          float* oa = ob + (size_t)(rr + qq) * OD + cc;
          asm volatile("global_store_dword %0, %1, off" :: "v"(oa), "v"(v) : "memory");
        }
      }
      int tt = (t + 1 < SD) ? (t + 1) : t;
      const float* ta = td + (size_t)tt * BD + grow;
      asm volatile("global_load_dword %0, %1, off" : "=&v"(tdn) : "v"(ta) : "memory");
      ISSUE_CHUNK(0) ISSUE_CHUNK(1) ISSUE_CHUNK(2) ISSUE_CHUNK(3)
      ISSUE_CHUNK(4) ISSUE_CHUNK(5) ISSUE_CHUNK(6) ISSUE_CHUNK(7)
    }
  }

  // ---- tail: rows SD-2 and SD-1 ----
  __syncthreads();   // iter SD-1 partials visible
  if (m < 8 && wv == 0) {
    float* ob = out + (size_t)(SD - 2) * (BD * OD) + (size_t)(gid * 16) * OD + m * 16;
    #pragma unroll
    for (int qq = 0; qq < 4; ++qq) {
      float v = obufP[(SD - 1) & 1][0][rr + qq][cc] +
                obufP[(SD - 1) & 1][1][rr + qq][cc] + lb;
      float* oa = ob + (size_t)(rr + qq) * OD + cc;
      asm volatile("global_store_dword %0, %1, off" :: "v"(oa), "v"(v) : "memory");
    }
  }
  if (m < 8 && wv >= 2) {
    const char* csrc = hb + (size_t)(SD % 3) * 16384 + (size_t)(khalf * 8) * 1024 + aoff;
    asm volatile("s_waitcnt vmcnt(0)" ::: "memory");
    __builtin_amdgcn_sched_barrier(0);
    RETRY_CHUNK(0) RETRY_CHUNK(1) RETRY_CHUNK(2) RETRY_CHUNK(3)
    RETRY_CHUNK(4) RETRY_CHUNK(5) RETRY_CHUNK(6) RETRY_CHUNK(7)
    f32x4 os = {0.f, 0.f, 0.f, 0.f};
    OP_CHUNK(0) OP_CHUNK(1) OP_CHUNK(2) OP_CHUNK(3)
    OP_CHUNK(4) OP_CHUNK(5) OP_CHUNK(6) OP_CHUNK(7)
    #pragma unroll
    for (int qq = 0; qq < 4; ++qq)
      obufP[SD & 1][khalf][rr + qq][cc] = os[qq];
  }
  __syncthreads();
  if (m < 8 && wv == 0) {
    float* ob = out + (size_t)(SD - 1) * (BD * OD) + (size_t)(gid * 16) * OD + m * 16;
    #pragma unroll
    for (int qq = 0; qq < 4; ++qq) {
      float v = obufP[SD & 1][0][rr + qq][cc] +
                obufP[SD & 1][1][rr + qq][cc] + lb;
      float* oa = ob + (size_t)(rr + qq) * OD + cc;
      asm volatile("global_store_dword %0, %1, off" :: "v"(oa), "v"(v) : "memory");
    }
  }
}

// ---------------- launcher ----------------
extern "C" void kernel_launch(void* const* d_in, const int* in_sizes, int n_in,
                              void* d_out, int out_size, void* d_ws, size_t ws_size,
                              hipStream_t stream) {
  const float* C    = (const float*)d_in[0];
  const float* t    = (const float*)d_in[1];
  // d_in[2] = mask (unused by reference)
  const float* Wih  = (const float*)d_in[3];
  const float* Whh  = (const float*)d_in[4];
  const float* bih  = (const float*)d_in[5];
  const float* bhh  = (const float*)d_in[6];
  const float* linW = (const float*)d_in[7];
  const float* linb = (const float*)d_in[8];
  const float* tW   = (const float*)d_in[9];
  const float* tb   = (const float*)d_in[10];
  float* out = (float*)d_out;

  char* ws = (char*)d_ws;
  float*          CW    = (float*)(ws + 0);                 // 2,097,152
  float*          u     = (float*)(ws + 2097152);           // 8,192
  float*          ub    = (float*)(ws + 2105344);           // 8,192
  float*          td    = (float*)(ws + 2113536);           // 524,288
  unsigned short* whhb  = (unsigned short*)(ws + 2637824);  // 2,097,152
  unsigned short* linwb = (unsigned short*)(ws + 4734976);  // 131,072
  unsigned short* hbuf  = (unsigned short*)(ws + 4866048);  // 786,432
  if (ws_size < 5652480) return;

  k_poison<<<192, 256, 0, stream>>>((unsigned int*)hbuf);
  k_cvt<<<4096, 256, 0, stream>>>(Whh, linW, whhb, linwb);
  k_td <<<512, 256, 0, stream>>>(t, td);
  k_u  <<<8, 256, 0, stream>>>(Wih, tW, tb, bih, bhh, u, ub);
  k_cw <<<dim3(32, 16), 1024, 0, stream>>>(C, Wih, ub, CW);
  k_main<<<256, 256, 0, stream>>>(CW, u, td, whhb, linwb, linb, hbuf, out);
}

// Round 16
// 1712.332 us; speedup vs baseline: 1.2122x; 1.2122x over previous
//
#include <hip/hip_runtime.h>
#include <stdint.h>

// LSTMTimeDecoder on MI355X — round 16.
// Mechanism found: vmcnt retires IN ORDER (m135), and every prior round issued
// the sc0sc1 h-store before the consume loads in the SAME wave's queue — so
// every load-check transitively waited the store's HBM write-through ack
// (~1-2k cy under load). Fix: wave-specialized queues.
//   wave 3: sole storer. Cell h -> hcell LDS (B2); wave 3 reads hcell, issues
//           1KB F + repoison (sc0sc1, SAME swizzled addresses -> slot WAW is
//           same-wave, anchored by a pre-F vmcnt(0) on ops aged a full step).
//           td issued BEFORE stores => vmcnt(2) at cell retires td only.
//   waves 0,1: pure-load queues. sleep(6) -> td + 8x dwordx4 (linear image
//           copy) -> vmcnt(0) (= pure load RT) -> sentinel check -> masked
//           retry -> scatter into double-buffered hlds[t&1].
//   wave 2: out-projection (r14-verified) from hlds[cur]; plain out stores.
// Raw s_barrier + lgkmcnt only. Gates / cell / W-in-regs / lwlds / image
// swizzle are r14-verified and byte-identical.

#define HD 512
#define BD 256
#define SD 512
#define OD 128
#define SENT 0xFF80FF80u

typedef __attribute__((ext_vector_type(8))) short short8;
typedef __attribute__((ext_vector_type(4))) float f32x4;
typedef __attribute__((ext_vector_type(4))) unsigned int u32x4;

static __device__ __forceinline__ unsigned short f2bf(float x) {
  unsigned int u = __float_as_uint(x);
  u += 0x7fffu + ((u >> 16) & 1u);
  return (unsigned short)(u >> 16);
}
static __device__ __forceinline__ float sigm(float x) {
  return 1.0f / (1.0f + __expf(-x));
}
static __device__ __forceinline__ float tanhf_(float x) {
  x = fminf(15.f, fmaxf(-15.f, x));
  float e = __expf(2.f * x);
  return (e - 1.f) / (e + 1.f);
}
static __device__ __forceinline__ int badchk8(short8 v) {
  u32x4 w;
  __builtin_memcpy(&w, &v, 16);
  return (w.x == SENT) | (w.y == SENT) | (w.z == SENT) | (w.w == SENT);
}
#define KEEPALIVE(x) asm volatile("" : "+v"(x))

// ---------------- prep kernels (verified rounds 1-15) ----------------
__global__ __launch_bounds__(256) void k_cvt(const float* __restrict__ whh,
                                             const float* __restrict__ linw,
                                             unsigned short* __restrict__ whhb,
                                             unsigned short* __restrict__ linwb) {
  int i = blockIdx.x * 256 + threadIdx.x;
  whhb[i] = f2bf(whh[i]);
  if (i < OD * HD) linwb[i] = f2bf(linw[i]);
}

__global__ __launch_bounds__(256) void k_td(const float* __restrict__ t,
                                            float* __restrict__ td) {
  int i = blockIdx.x * 256 + threadIdx.x;
  float v = 0.f;
  if (i >= BD) v = t[i] - t[i - BD];
  td[i] = v;
}

__global__ __launch_bounds__(256) void k_u(const float* __restrict__ wih,
                                           const float* __restrict__ tw,
                                           const float* __restrict__ tb,
                                           const float* __restrict__ bih,
                                           const float* __restrict__ bhh,
                                           float* __restrict__ u,
                                           float* __restrict__ ub) {
  int gc = blockIdx.x * 256 + threadIdx.x;
  const float4* w4 = (const float4*)(wih + (size_t)gc * (2 * HD) + HD);
  const float4* t4 = (const float4*)tw;
  const float4* b4 = (const float4*)tb;
  float a = 0.f, b = 0.f;
  for (int k = 0; k < HD / 4; ++k) {
    float4 w = w4[k], tv = t4[k], bv = b4[k];
    a += w.x * tv.x + w.y * tv.y + w.z * tv.z + w.w * tv.w;
    b += w.x * bv.x + w.y * bv.y + w.z * bv.z + w.w * bv.w;
  }
  u[gc] = a;
  ub[gc] = b + bih[gc] + bhh[gc];
}

__global__ __launch_bounds__(1024) void k_cw(const float* __restrict__ C,
                                             const float* __restrict__ wih,
                                             const float* __restrict__ ub,
                                             float* __restrict__ CW) {
  int gc = blockIdx.x * 64 + (threadIdx.x & 63);
  int b  = blockIdx.y * 16 + (threadIdx.x >> 6);
  const float4* c4 = (const float4*)(C + (size_t)b * HD);
  const float4* w4 = (const float4*)(wih + (size_t)gc * (2 * HD));
  float acc = 0.f;
  for (int k = 0; k < HD / 4; ++k) {
    float4 cv = c4[k], wv = w4[k];
    acc += cv.x * wv.x + cv.y * wv.y + cv.z * wv.z + cv.w * wv.w;
  }
  CW[(size_t)b * (4 * HD) + gc] = acc + ub[gc];
}

__global__ __launch_bounds__(256) void k_poison(unsigned int* __restrict__ hbuf) {
  u32x4 s = {SENT, SENT, SENT, SENT};
  unsigned int* p = hbuf + (size_t)(blockIdx.x * 256 + threadIdx.x) * 4;
  asm volatile("global_store_dwordx4 %0, %1, off sc0 sc1" :: "v"(p), "v"(s) : "memory");
}

// ---------------- main recurrent kernel ----------------
__global__ __launch_bounds__(256, 1) void k_main(
    const float* __restrict__ CW, const float* __restrict__ u,
    const float* __restrict__ td, const unsigned short* __restrict__ whhb,
    const unsigned short* __restrict__ linwb, const float* __restrict__ linb,
    unsigned short* __restrict__ hbuf, float* __restrict__ out)
{
  __shared__ __align__(16) unsigned short hlds[2][16 * HD]; // 32KB double-buffered image
  __shared__ __align__(16) unsigned short lwlds[16 * HD];   // 16KB linW slice
  __shared__ __align__(16) unsigned short hcell[16 * 32];   // 1KB cell handoff
  __shared__ float gbuf[4][16][33];

  const int tid  = threadIdx.x;
  const int lane = tid & 63;
  const int wv   = tid >> 6;          // wave role: 0,1 load; 2 out; 3 store
  const int gid  = blockIdx.x & 15;   // batch group
  const int m    = blockIdx.x >> 4;   // member: h-cols [m*32, m*32+32)

  // ---- W_hh fragments -> registers via asm (r14-verified layout) ----
  short8 w0[16], w1[16];
  {
    const unsigned short* wb =
        whhb + ((size_t)wv * HD + m * 32 + (lane & 15)) * HD + (lane >> 4) * 8;
    #pragma unroll
    for (int kk = 0; kk < 16; ++kk) {
      asm volatile("global_load_dwordx4 %0, %2, off\n\t"
                   "global_load_dwordx4 %1, %3, off"
                   : "=&v"(w0[kk]), "=&v"(w1[kk])
                   : "v"(wb + kk * 32), "v"(wb + 16 * HD + kk * 32) : "memory");
    }
  }

  // ---- linW slice -> LDS (r14-verified staging, XOR image) ----
  if (m < 8) {
    for (int i = tid; i < 16 * 64; i += 256) {
      int rl = i >> 6, c = i & 63;
      *(short8*)((char*)lwlds + (size_t)rl * 1024 + (size_t)c * 16) =
          *(const short8*)((const char*)linwb + (size_t)(m * 16 + rl) * 1024 +
                           (size_t)((c ^ (rl & 7)) * 16));
    }
  }

  // ---- per-thread cell constants (r14-verified) ----
  const int r    = tid >> 4;
  const int jl0  = (tid & 15) * 2;
  const int grow = gid * 16 + r;
  const int col0 = m * 32 + jl0;
  float cwr[8], ur[8];
  #pragma unroll
  for (int g = 0; g < 4; ++g) {
    int col = g * HD + col0;
    cwr[g * 2]     = CW[(size_t)grow * (4 * HD) + col];
    cwr[g * 2 + 1] = CW[(size_t)grow * (4 * HD) + col + 1];
    ur[g * 2]      = u[col];
    ur[g * 2 + 1]  = u[col + 1];
  }
  float cs0 = 0.f, cs1 = 0.f;
  float lb = 0.f;
  if (m < 8) lb = linb[m * 16 + (lane & 15)];

  char* hb = (char*)hbuf + (size_t)gid * 49152;   // 3 slots x 16KB (r14 image)

  const int arow  = lane & 15;
  const int akoff = lane >> 4;
  const int axor  = arow & 7;
  const int lrow  = lane & 15;
  const int lxor  = (lrow & 7) << 4;
  // wave-3 store addressing (swizzled image; SAME formula for F and repoison)
  const int srow   = lane >> 2;
  const int sj     = lane & 3;
  const int sboff  = srow * 1024 + (((m * 4 + sj) ^ (srow & 7)) << 4);

  short8 a0{}, a1{}, a2{}, a3{}, a4{}, a5{}, a6{}, a7{};
  float  tdn = 0.f, tdv = 0.f;
  u32x4  sv = {SENT, SENT, SENT, SENT};

  #pragma unroll
  for (int i = 0; i < 8; ++i) { KEEPALIVE(cwr[i]); KEEPALIVE(ur[i]); }
  KEEPALIVE(lb);
  asm volatile("s_waitcnt vmcnt(0)" ::: "memory");   // W + constants resident
  __builtin_amdgcn_sched_barrier(0);
  __syncthreads();                                    // lwlds staged (once)

  for (int t = 0; t < SD; ++t) {
    const size_t oN = (size_t)((t + 1) % 3) * 16384;  // h_{t+1} slot
    const size_t oR = (size_t)((t + 2) % 3) * 16384;  // h_{t-1} slot (repoison)
    const int cur = t & 1, nxt = cur ^ 1;
    const char* hcur = (const char*)&hlds[cur][0];

    // ---- gates = h_t @ W^T (all waves; A from hlds[cur], B = registers) ----
    f32x4 acc0 = {0.f, 0.f, 0.f, 0.f}, acc1 = {0.f, 0.f, 0.f, 0.f};
    if (t > 0) {
      #pragma unroll
      for (int kk = 0; kk < 16; ++kk) {
        short8 a = *(const short8*)(hcur + (size_t)arow * 1024 +
                                    (size_t)(((kk * 4 + akoff) ^ axor) << 4));
        acc0 = __builtin_amdgcn_mfma_f32_16x16x32_bf16(a, w0[kk], acc0, 0, 0, 0);
        acc1 = __builtin_amdgcn_mfma_f32_16x16x32_bf16(a, w1[kk], acc1, 0, 0, 0);
      }
    }
    {
      int rr = (lane >> 4) * 4, cc = lane & 15;
      #pragma unroll
      for (int qq = 0; qq < 4; ++qq) {
        gbuf[wv][rr + qq][cc]      = acc0[qq];
        gbuf[wv][rr + qq][16 + cc] = acc1[qq];
      }
    }
    asm volatile("s_waitcnt lgkmcnt(0)" ::: "memory");
    __builtin_amdgcn_s_barrier();          // B1: gbuf ready

    // ---- td retirement per role (in-order queues; loads precede stores) ----
    if (wv == 2)      asm volatile("s_waitcnt vmcnt(0)" ::: "memory"); // old+fast
    else if (wv == 3) asm volatile("s_waitcnt vmcnt(2)" ::: "memory"); // retires td, NOT F/rp
    __builtin_amdgcn_sched_barrier(0);
    tdv = (t > 0) ? tdn : 0.f;

    // ---- cell (2 elems/thread) -> hcell LDS handoff ----
    {
      float p0i = gbuf[0][r][jl0]     + cwr[0] + tdv * ur[0];
      float p1i = gbuf[0][r][jl0 + 1] + cwr[1] + tdv * ur[1];
      float p0f = gbuf[1][r][jl0]     + cwr[2] + tdv * ur[2];
      float p1f = gbuf[1][r][jl0 + 1] + cwr[3] + tdv * ur[3];
      float p0g = gbuf[2][r][jl0]     + cwr[4] + tdv * ur[4];
      float p1g = gbuf[2][r][jl0 + 1] + cwr[5] + tdv * ur[5];
      float p0o = gbuf[3][r][jl0]     + cwr[6] + tdv * ur[6];
      float p1o = gbuf[3][r][jl0 + 1] + cwr[7] + tdv * ur[7];
      cs0 = sigm(p0f) * cs0 + sigm(p0i) * tanhf_(p0g);
      cs1 = sigm(p1f) * cs1 + sigm(p1i) * tanhf_(p1g);
      float h0 = sigm(p0o) * tanhf_(cs0);
      float h1 = sigm(p1o) * tanhf_(cs1);
      unsigned int hp = (unsigned int)f2bf(h0) | ((unsigned int)f2bf(h1) << 16);
      *(unsigned int*)((char*)hcell + (size_t)(r * 64) + (size_t)(jl0 * 2)) = hp;
    }
    asm volatile("s_waitcnt lgkmcnt(0)" ::: "memory");
    __builtin_amdgcn_s_barrier();          // B2: hcell ready

    if (wv == 3) {
      // WAW anchor: rp(t-1) (same addresses as this F) must be at L3 first.
      // Its ops are a full step old => usually free.
      asm volatile("s_waitcnt vmcnt(0)" ::: "memory");
      __builtin_amdgcn_sched_barrier(0);
      u32x4 hv = *(const u32x4*)((const char*)hcell + (size_t)lane * 16);
      asm volatile("s_waitcnt lgkmcnt(0)" ::: "memory");
      __builtin_amdgcn_sched_barrier(0);
      {  // td FIRST (oldest in queue), then F, then repoison
        int tt = (t + 1 < SD) ? (t + 1) : t;
        const float* ta = td + (size_t)tt * BD + grow;
        asm volatile("global_load_dword %0, %1, off" : "=&v"(tdn) : "v"(ta) : "memory");
      }
      asm volatile("global_store_dwordx4 %0, %1, off sc0 sc1"
                   :: "v"(hb + oN + sboff), "v"(hv) : "memory");
      asm volatile("global_store_dwordx4 %0, %1, off sc0 sc1"
                   :: "v"(hb + oR + sboff), "v"(sv) : "memory");
    } else if (wv == 2) {
      if (m < 8 && t > 0) {   // out row t-1 from hlds[cur] (r14-verified block)
        f32x4 osA = {0.f, 0.f, 0.f, 0.f}, osB = {0.f, 0.f, 0.f, 0.f};
        #pragma unroll
        for (int kk = 0; kk < 8; ++kk) {
          short8 aA = *(const short8*)(hcur + (size_t)arow * 1024 +
                                       (size_t)(((kk * 4 + akoff) ^ axor) << 4));
          short8 aB = *(const short8*)(hcur + (size_t)arow * 1024 +
                                       (size_t)((((kk + 8) * 4 + akoff) ^ axor) << 4));
          short8 bA = *(const short8*)((const char*)lwlds + (size_t)lrow * 1024 +
                                       (size_t)((kk * 64 + akoff * 16) ^ lxor));
          short8 bB = *(const short8*)((const char*)lwlds + (size_t)lrow * 1024 +
                                       (size_t)(((kk + 8) * 64 + akoff * 16) ^ lxor));
          osA = __builtin_amdgcn_mfma_f32_16x16x32_bf16(aA, bA, osA, 0, 0, 0);
          osB = __builtin_amdgcn_mfma_f32_16x16x32_bf16(aB, bB, osB, 0, 0, 0);
        }
        float* ob = out + (size_t)(t - 1) * (BD * OD) + (size_t)(gid * 16) * OD + m * 16;
        int rr = (lane >> 4) * 4, cc = lane & 15;
        #pragma unroll
        for (int qq = 0; qq < 4; ++qq) {
          float vst = osA[qq] + osB[qq] + lb;
          float* oa = ob + (size_t)(rr + qq) * OD + cc;
          asm volatile("global_store_dword %0, %1, off" :: "v"(oa), "v"(vst) : "memory");
        }
      }
      {  // td for next cell (queue: plain out stores + td; vmcnt(0) at cell ~free)
        int tt = (t + 1 < SD) ? (t + 1) : t;
        const float* ta = td + (size_t)tt * BD + grow;
        asm volatile("global_load_dword %0, %1, off" : "=&v"(tdn) : "v"(ta) : "memory");
      }
    } else {
      // ---- loader waves 0,1: PURE-LOAD queue ----
      __builtin_amdgcn_s_sleep(6);   // ~384 cy: let peers' F stores land
      {
        int tt = (t + 1 < SD) ? (t + 1) : t;
        const float* ta = td + (size_t)tt * BD + grow;
        asm volatile("global_load_dword %0, %1, off" : "=&v"(tdn) : "v"(ta) : "memory");
      }
      const char* nsrc = hb + oN + (size_t)(wv * 8) * 1024 + (size_t)lane * 16;
      asm volatile(
          "global_load_dwordx4 %0, %8, off sc0 sc1\n\t"
          "global_load_dwordx4 %1, %9, off sc0 sc1\n\t"
          "global_load_dwordx4 %2, %10, off sc0 sc1\n\t"
          "global_load_dwordx4 %3, %11, off sc0 sc1\n\t"
          "global_load_dwordx4 %4, %12, off sc0 sc1\n\t"
          "global_load_dwordx4 %5, %13, off sc0 sc1\n\t"
          "global_load_dwordx4 %6, %14, off sc0 sc1\n\t"
          "global_load_dwordx4 %7, %15, off sc0 sc1\n\t"
          "s_waitcnt vmcnt(0)"
          : "=&v"(a0), "=&v"(a1), "=&v"(a2), "=&v"(a3),
            "=&v"(a4), "=&v"(a5), "=&v"(a6), "=&v"(a7)
          : "v"(nsrc), "v"(nsrc + 1024), "v"(nsrc + 2048), "v"(nsrc + 3072),
            "v"(nsrc + 4096), "v"(nsrc + 5120), "v"(nsrc + 6144), "v"(nsrc + 7168)
          : "memory");
      __builtin_amdgcn_sched_barrier(0);
      {
        int b0 = badchk8(a0), b1 = badchk8(a1), b2 = badchk8(a2), b3 = badchk8(a3);
        int b4 = badchk8(a4), b5 = badchk8(a5), b6 = badchk8(a6), b7 = badchk8(a7);
        int guard = 0;
        while (__any(b0 | b1 | b2 | b3 | b4 | b5 | b6 | b7)) {
          if (++guard > (1 << 16)) break;
          __builtin_amdgcn_s_sleep(2);
          if (b0) asm volatile("global_load_dwordx4 %0, %1, off sc0 sc1" : "=&v"(a0) : "v"(nsrc) : "memory");
          if (b1) asm volatile("global_load_dwordx4 %0, %1, off sc0 sc1" : "=&v"(a1) : "v"(nsrc + 1024) : "memory");
          if (b2) asm volatile("global_load_dwordx4 %0, %1, off sc0 sc1" : "=&v"(a2) : "v"(nsrc + 2048) : "memory");
          if (b3) asm volatile("global_load_dwordx4 %0, %1, off sc0 sc1" : "=&v"(a3) : "v"(nsrc + 3072) : "memory");
          if (b4) asm volatile("global_load_dwordx4 %0, %1, off sc0 sc1" : "=&v"(a4) : "v"(nsrc + 4096) : "memory");
          if (b5) asm volatile("global_load_dwordx4 %0, %1, off sc0 sc1" : "=&v"(a5) : "v"(nsrc + 5120) : "memory");
          if (b6) asm volatile("global_load_dwordx4 %0, %1, off sc0 sc1" : "=&v"(a6) : "v"(nsrc + 6144) : "memory");
          if (b7) asm volatile("global_load_dwordx4 %0, %1, off sc0 sc1" : "=&v"(a7) : "v"(nsrc + 7168) : "memory");
          asm volatile("s_waitcnt vmcnt(0)" ::: "memory");
          __builtin_amdgcn_sched_barrier(0);
          b0 = badchk8(a0); b1 = badchk8(a1); b2 = badchk8(a2); b3 = badchk8(a3);
          b4 = badchk8(a4); b5 = badchk8(a5); b6 = badchk8(a6); b7 = badchk8(a7);
        }
      }
      // scatter validated image rows into hlds[nxt] (linear copy)
      {
        char* dst = (char*)&hlds[nxt][0] + (size_t)(wv * 8) * 1024 + (size_t)lane * 16;
        *(short8*)(dst)        = a0;
        *(short8*)(dst + 1024) = a1;
        *(short8*)(dst + 2048) = a2;
        *(short8*)(dst + 3072) = a3;
        *(short8*)(dst + 4096) = a4;
        *(short8*)(dst + 5120) = a5;
        *(short8*)(dst + 6144) = a6;
        *(short8*)(dst + 7168) = a7;
      }
    }

    asm volatile("s_waitcnt lgkmcnt(0)" ::: "memory");
    __builtin_amdgcn_s_barrier();          // B3: hlds[nxt] = h_{t+1}
  }

  // ---- tail: out row SD-1 from hlds[SD&1] (= h_SD) ----
  if (wv == 2 && m < 8) {
    const char* hcur = (const char*)&hlds[SD & 1][0];
    f32x4 osA = {0.f, 0.f, 0.f, 0.f}, osB = {0.f, 0.f, 0.f, 0.f};
    #pragma unroll
    for (int kk = 0; kk < 8; ++kk) {
      short8 aA = *(const short8*)(hcur + (size_t)arow * 1024 +
                                   (size_t)(((kk * 4 + akoff) ^ axor) << 4));
      short8 aB = *(const short8*)(hcur + (size_t)arow * 1024 +
                                   (size_t)((((kk + 8) * 4 + akoff) ^ axor) << 4));
      short8 bA = *(const short8*)((const char*)lwlds + (size_t)lrow * 1024 +
                                   (size_t)((kk * 64 + akoff * 16) ^ lxor));
      short8 bB = *(const short8*)((const char*)lwlds + (size_t)lrow * 1024 +
                                   (size_t)(((kk + 8) * 64 + akoff * 16) ^ lxor));
      osA = __builtin_amdgcn_mfma_f32_16x16x32_bf16(aA, bA, osA, 0, 0, 0);
      osB = __builtin_amdgcn_mfma_f32_16x16x32_bf16(aB, bB, osB, 0, 0, 0);
    }
    float* ob = out + (size_t)(SD - 1) * (BD * OD) + (size_t)(gid * 16) * OD + m * 16;
    int rr = (lane >> 4) * 4, cc = lane & 15;
    #pragma unroll
    for (int qq = 0; qq < 4; ++qq) {
      float vst = osA[qq] + osB[qq] + lb;
      float* oa = ob + (size_t)(rr + qq) * OD + cc;
      asm volatile("global_store_dword %0, %1, off" :: "v"(oa), "v"(vst) : "memory");
    }
  }
}

// ---------------- launcher ----------------
extern "C" void kernel_launch(void* const* d_in, const int* in_sizes, int n_in,
                              void* d_out, int out_size, void* d_ws, size_t ws_size,
                              hipStream_t stream) {
  const float* C    = (const float*)d_in[0];
  const float* t    = (const float*)d_in[1];
  // d_in[2] = mask (unused by reference)
  const float* Wih  = (const float*)d_in[3];
  const float* Whh  = (const float*)d_in[4];
  const float* bih  = (const float*)d_in[5];
  const float* bhh  = (const float*)d_in[6];
  const float* linW = (const float*)d_in[7];
  const float* linb = (const float*)d_in[8];
  const float* tW   = (const float*)d_in[9];
  const float* tb   = (const float*)d_in[10];
  float* out = (float*)d_out;

  char* ws = (char*)d_ws;
  float*          CW    = (float*)(ws + 0);                 // 2,097,152
  float*          u     = (float*)(ws + 2097152);           // 8,192
  float*          ub    = (float*)(ws + 2105344);           // 8,192
  float*          td    = (float*)(ws + 2113536);           // 524,288
  unsigned short* whhb  = (unsigned short*)(ws + 2637824);  // 2,097,152
  unsigned short* linwb = (unsigned short*)(ws + 4734976);  // 131,072
  unsigned short* hbuf  = (unsigned short*)(ws + 4866048);  // 786,432
  if (ws_size < 5652480) return;

  k_poison<<<192, 256, 0, stream>>>((unsigned int*)hbuf);
  k_cvt<<<4096, 256, 0, stream>>>(Whh, linW, whhb, linwb);
  k_td <<<512, 256, 0, stream>>>(t, td);
  k_u  <<<8, 256, 0, stream>>>(Wih, tW, tb, bih, bhh, u, ub);
  k_cw <<<dim3(32, 16), 1024, 0, stream>>>(C, Wih, ub, CW);
  k_main<<<256, 256, 0, stream>>>(CW, u, td, whhb, linwb, linb, hbuf, out);
}